// Round 5
// baseline (156.359 us; speedup 1.0000x reference)
//
#include <hip/hip_runtime.h>
#include <cfloat>
#include <climits>

#define NB 64
#define NA 2000
#define NA0 1600
#define NC 20
#define NM 100

__device__ __forceinline__ void anchor_geom(int a, float& axc, float& ayc, float& st) {
    if (a < NA0) {
        st = 16.0f;
        int x = a % 40, y = a / 40;
        axc = ((float)x + 0.5f) * 16.0f;
        ayc = ((float)y + 0.5f) * 16.0f;
    } else {
        st = 32.0f;
        int aa = a - NA0;
        int x = aa % 20, y = aa / 20;
        axc = ((float)x + 0.5f) * 32.0f;
        ayc = ((float)y + 0.5f) * 32.0f;
    }
}

// Wave64 u32 max/min reduce via DPP (rocPRIM pattern): row_shr 1/2/4/8 then
// row_bcast15 (rows 1,3) + row_bcast31 (rows 2,3); full reduction lands in
// lane 63; readlane -> SGPR broadcast. old = x, bound_ctrl=false so invalid
// lanes fold x with itself (identity-safe for both max and min).
__device__ __forceinline__ unsigned int wave_max_u32(unsigned int x) {
    unsigned int y;
    y = (unsigned)__builtin_amdgcn_update_dpp((int)x, (int)x, 0x111, 0xf, 0xf, false); x = max(x, y);
    y = (unsigned)__builtin_amdgcn_update_dpp((int)x, (int)x, 0x112, 0xf, 0xf, false); x = max(x, y);
    y = (unsigned)__builtin_amdgcn_update_dpp((int)x, (int)x, 0x114, 0xf, 0xf, false); x = max(x, y);
    y = (unsigned)__builtin_amdgcn_update_dpp((int)x, (int)x, 0x118, 0xf, 0xf, false); x = max(x, y);
    y = (unsigned)__builtin_amdgcn_update_dpp((int)x, (int)x, 0x142, 0xa, 0xf, false); x = max(x, y);
    y = (unsigned)__builtin_amdgcn_update_dpp((int)x, (int)x, 0x143, 0xc, 0xf, false); x = max(x, y);
    return (unsigned)__builtin_amdgcn_readlane((int)x, 63);
}
__device__ __forceinline__ unsigned int wave_min_u32(unsigned int x) {
    unsigned int y;
    y = (unsigned)__builtin_amdgcn_update_dpp((int)x, (int)x, 0x111, 0xf, 0xf, false); x = min(x, y);
    y = (unsigned)__builtin_amdgcn_update_dpp((int)x, (int)x, 0x112, 0xf, 0xf, false); x = min(x, y);
    y = (unsigned)__builtin_amdgcn_update_dpp((int)x, (int)x, 0x114, 0xf, 0xf, false); x = min(x, y);
    y = (unsigned)__builtin_amdgcn_update_dpp((int)x, (int)x, 0x118, 0xf, 0xf, false); x = min(x, y);
    y = (unsigned)__builtin_amdgcn_update_dpp((int)x, (int)x, 0x142, 0xa, 0xf, false); x = min(x, y);
    y = (unsigned)__builtin_amdgcn_update_dpp((int)x, (int)x, 0x143, 0xc, 0xf, false); x = min(x, y);
    return (unsigned)__builtin_amdgcn_readlane((int)x, 63);
}

__global__ __launch_bounds__(256) void k_decode(const float* __restrict__ l0, const float* __restrict__ l1,
                                                const float* __restrict__ gt_boxes, const int* __restrict__ num_gts,
                                                float4* __restrict__ dec, float* __restrict__ qq,
                                                unsigned long long* __restrict__ fgw, unsigned int* __restrict__ cm,
                                                unsigned int* __restrict__ bg) {
    int b = blockIdx.y;
    int a = blockIdx.x * 256 + threadIdx.x;
    int lane = threadIdx.x & 63;
    __shared__ float4 sext[NM];   // gl, gr, gt, gb
    __shared__ float2 sctr[NM];   // g.x, g.y
    __shared__ int sng;
    if (threadIdx.x < NM) {
        float4 g = ((const float4*)gt_boxes)[b * NM + threadIdx.x];
        g.x *= 640.0f; g.y *= 640.0f; g.z *= 640.0f; g.w *= 640.0f;
        sext[threadIdx.x] = make_float4(g.x - 0.5f * g.z, g.x + 0.5f * g.z,
                                        g.y - 0.5f * g.w, g.y + 0.5f * g.w);
        sctr[threadIdx.x] = make_float2(g.x, g.y);
    }
    if (threadIdx.x == 0) sng = num_gts[b];
    __syncthreads();
    if (a >= NA) return;

    float v[25];
    if (a < NA0) {
        const float* p = l0 + (size_t)b * 25 * NA0 + a;
#pragma unroll
        for (int c = 0; c < 25; c++) v[c] = p[(size_t)c * NA0];
    } else {
        const float* p = l1 + (size_t)b * 25 * 400 + (a - NA0);
#pragma unroll
        for (int c = 0; c < 25; c++) v[c] = p[(size_t)c * 400];
    }
    float axc, ayc, st;
    anchor_geom(a, axc, ayc, st);
    float gx, gy;
    if (a < NA0) { gx = (float)(a % 40); gy = (float)(a / 40); }
    else { int aa = a - NA0; gx = (float)(aa % 20); gy = (float)(aa / 20); }
    float4 pb;
    pb.x = (v[0] + gx) * st;
    pb.y = (v[1] + gy) * st;
    pb.z = expf(v[2]) * st;
    pb.w = expf(v[3]) * st;
    dec[(size_t)b * NA + a] = pb;

    float sob = 1.0f / (1.0f + __expf(-v[4]));
    float d[NC];
    float s = 0.0f;
#pragma unroll
    for (int c = 0; c < NC; c++) {
        float sc = 1.0f / (1.0f + __expf(-v[5 + c]));
        float p = sqrtf(sc * sob);
        float lp = __logf(p + 1e-12f);
        float lq = __logf(1.0f - p + 1e-12f);
        s += -lq;
        d[c] = lq - lp;
    }
#pragma unroll
    for (int c = 0; c < NC; c++)
        qq[((size_t)b * NC + c) * NA + a] = s + d[c];

    int ng = sng;
    int f = 0;
    float rst = 2.5f * st;
    for (int m = 0; m < ng; m++) {
        float4 e = sext[m];
        float2 cc = sctr[m];
        bool ib = (axc > e.x) && (axc < e.y) && (ayc > e.z) && (ayc < e.w);
        bool ic = (axc > cc.x - rst) && (axc < cc.x + rst) && (ayc > cc.y - rst) && (ayc < cc.y + rst);
        if (ib || ic) { f = 1; break; }
    }
    unsigned long long mk = __ballot(f);
    if (lane == 0) fgw[(size_t)b * 32 + (a >> 6)] = mk;
    cm[(size_t)b * NA + a] = 0;
    bg[(size_t)b * NA + a] = 0xFFFFFFFFu;
}

// one wave per (b, m) row; 4 waves per block. Packed u32 keys + destructive extraction.
__global__ __launch_bounds__(256) void k_assign(const float* __restrict__ gt_boxes, const int* __restrict__ gt_classes,
                                                const int* __restrict__ num_gts, const float4* __restrict__ dec,
                                                const float* __restrict__ qq, const unsigned long long* __restrict__ fgw,
                                                unsigned int* __restrict__ cm, unsigned int* __restrict__ bg) {
    int wave = threadIdx.x >> 6;
    int lane = threadIdx.x & 63;
    int row = blockIdx.x * 4 + wave;
    int b = row / NM, m = row - b * NM;
    if (m >= num_gts[b]) return;

    float4 g = ((const float4*)gt_boxes)[b * NM + m];
    g.x *= 640.0f; g.y *= 640.0f; g.z *= 640.0f; g.w *= 640.0f;
    int tc = gt_classes[b * NM + m];
    const float* qrow = qq + ((size_t)b * NC + tc) * NA;
    size_t bNA = (size_t)b * NA;

    float glx = g.x - 0.5f * g.z, grx = g.x + 0.5f * g.z;
    float gty = g.y - 0.5f * g.w, gby = g.y + 0.5f * g.w;
    float areag = g.z * g.w;
    float c16l = g.x - 40.0f, c16r = g.x + 40.0f, c16t = g.y - 40.0f, c16b = g.y + 40.0f;
    float c32l = g.x - 80.0f, c32r = g.x + 80.0f, c32t = g.y - 80.0f, c32b = g.y + 80.0f;

    // ik: packed iou keys (desc-extract); ck: packed cost keys (asc-extract). idx in low 11 bits.
    unsigned int ik[32], ck[32];
#pragma unroll
    for (int j = 0; j < 32; j++) {
        int a = j * 64 + lane;
        bool inr = (j < 31) || (lane < 16);
        float stj = (j < 25) ? 16.0f : 32.0f;
        int rel = (j < 25) ? a : (a - NA0);
        int W = (j < 25) ? 40 : 20;
        int gyv = rel / W;
        int gxv = rel - gyv * W;
        float axc = ((float)gxv + 0.5f) * stj;
        float ayc = ((float)gyv + 0.5f) * stj;
        unsigned long long fw = fgw[(size_t)b * 32 + j];
        bool fc = (fw >> lane) & 1ULL;
        float4 pb = make_float4(0.f, 0.f, 1.f, 1.f);
        float clsc = 0.0f;
        if (inr) { pb = dec[bNA + a]; clsc = qrow[a]; }
        float tlx = fmaxf(glx, pb.x - 0.5f * pb.z);
        float tly = fmaxf(gty, pb.y - 0.5f * pb.w);
        float brx = fminf(grx, pb.x + 0.5f * pb.z);
        float bry = fminf(gby, pb.y + 0.5f * pb.w);
        float inter = (brx - tlx) * (bry - tly);
        bool ok = (tlx < brx) && (tly < bry);
        inter = ok ? inter : 0.0f;
        float iou = inter / ((areag + pb.z * pb.w) - inter + 1e-16f);
        bool ib = (axc > glx) && (axc < grx) && (ayc > gty) && (ayc < gby);
        bool ic = (j < 25) ? ((axc > c16l) && (axc < c16r) && (ayc > c16t) && (ayc < c16b))
                           : ((axc > c32l) && (axc < c32r) && (ayc > c32t) && (ayc < c32b));
        float cc = ((clsc - 3.0f * __logf(iou + 1e-8f)) + ((ib && ic) ? 0.0f : 1e5f)) + (fc ? 0.0f : 1e9f);
        float im = fc ? iou : 0.0f;
        ik[j] = inr ? ((__float_as_uint(im) & 0xFFFFF800u) | (unsigned)a) : 0u;
        ck[j] = inr ? ((__float_as_uint(cc) & 0xFFFFF800u) | (unsigned)a) : 0xFFFFFFFFu;
    }

    // Phase A: dk = max(1, trunc(sum of top-10 masked IoUs)) via destructive max-extraction.
    // Early break when the extracted max's value bits are 0: remaining contributions are +0.0f.
    float s10 = 0.0f;
#pragma unroll 1
    for (int k = 0; k < 10; k++) {
        unsigned int t[16];
#pragma unroll
        for (int h = 0; h < 16; h++) t[h] = max(ik[2 * h], ik[2 * h + 1]);
#pragma unroll
        for (int w = 8; w >= 1; w >>= 1)
#pragma unroll
            for (int h = 0; h < w; h++) t[h] = max(t[h], t[h + w]);
        unsigned int mx = wave_max_u32(t[0]);
        if ((mx & 0xFFFFF800u) == 0u) break;
        s10 += __uint_as_float(mx & 0xFFFFF800u);
#pragma unroll
        for (int j = 0; j < 32; j++) ik[j] = (ik[j] == mx) ? 0u : ik[j];
    }
    int dk = (int)s10;
    if (dk < 1) dk = 1;

    // Per-anchor argmin over rows (conflict resolution): key = cost[31:11] | m.
    // bg is monotone-decreasing; plain-load test first -> atomic only on strict improvement.
#pragma unroll
    for (int j = 0; j < 32; j++) {
        int a = j * 64 + lane;
        bool inr = (j < 31) || (lane < 16);
        if (inr) {
            unsigned int key = (ck[j] & 0xFFFFF800u) | (unsigned)m;
            if (key < bg[bNA + a]) atomicMin(&bg[bNA + a], key);
        }
    }

    // Phase B: dk destructive min-extractions on cost keys; mark matches
    unsigned int mb = 0;
#pragma unroll 1
    for (int k = 0; k < dk; k++) {
        unsigned int t[16];
#pragma unroll
        for (int h = 0; h < 16; h++) t[h] = min(ck[2 * h], ck[2 * h + 1]);
#pragma unroll
        for (int w = 8; w >= 1; w >>= 1)
#pragma unroll
            for (int h = 0; h < w; h++) t[h] = min(t[h], t[h + w]);
        unsigned int mn = wave_min_u32(t[0]);
#pragma unroll
        for (int j = 0; j < 32; j++) {
            bool e = (ck[j] == mn);
            mb |= e ? (1u << j) : 0u;
            ck[j] = e ? 0xFFFFFFFFu : ck[j];
        }
    }

    unsigned int inc = (1u << 20) + (unsigned)m;
#pragma unroll
    for (int j = 0; j < 32; j++) {
        if ((mb >> j) & 1u) atomicAdd(&cm[bNA + j * 64 + lane], inc);
    }
}

__global__ __launch_bounds__(256) void k_resolve(const float* __restrict__ l0, const float* __restrict__ l1,
                                                 const float* __restrict__ gt_boxes, const int* __restrict__ gt_classes,
                                                 const float4* __restrict__ dec,
                                                 const unsigned int* __restrict__ cm,
                                                 const unsigned int* __restrict__ bg,
                                                 float* __restrict__ partials) {
    int idx = blockIdx.x * 256 + threadIdx.x;
    int b = idx / NA, a = idx - b * NA;

    float objv;
    if (a < NA0) objv = l0[((size_t)b * 25 + 4) * NA0 + a];
    else         objv = l1[((size_t)b * 25 + 4) * 400 + (a - NA0)];

    unsigned int word = cm[idx];
    unsigned int c = word >> 20;
    bool fg = c > 0;
    float fgf = fg ? 1.0f : 0.0f;
    float lobj = (fmaxf(objv, 0.0f) + log1pf(expf(-fabsf(objv)))) - objv * fgf;
    float liou = 0.0f, lcls = 0.0f;

    if (fg) {
        float4 pb = dec[idx];
        int m;
        if (c == 1) m = (int)(word & 0xFFFFFu);
        else        m = (int)(bg[idx] & 0x7FFu);   // per-anchor argmin row
        float4 g = ((const float4*)gt_boxes)[b * NM + m];
        g.x *= 640.0f; g.y *= 640.0f; g.z *= 640.0f; g.w *= 640.0f;
        float tlx = fmaxf(pb.x - 0.5f * pb.z, g.x - 0.5f * g.z);
        float tly = fmaxf(pb.y - 0.5f * pb.w, g.y - 0.5f * g.w);
        float brx = fminf(pb.x + 0.5f * pb.z, g.x + 0.5f * g.z);
        float bry = fminf(pb.y + 0.5f * pb.w, g.y + 0.5f * g.w);
        float inter = (brx - tlx) * (bry - tly);
        bool ok = (tlx < brx) && (tly < bry);
        inter = ok ? inter : 0.0f;
        float iou = inter / ((pb.z * pb.w + g.z * g.w) - inter + 1e-16f);
        liou = 1.0f - iou * iou;
        float piou = iou;
        int tcm = gt_classes[b * NM + m];
#pragma unroll
        for (int c2 = 0; c2 < NC; c2++) {
            float x;
            if (a < NA0) x = l0[((size_t)b * 25 + 5 + c2) * NA0 + a];
            else         x = l1[((size_t)b * 25 + 5 + c2) * 400 + (a - NA0)];
            float t = (c2 == tcm) ? piou : 0.0f;
            lcls += (fmaxf(x, 0.0f) + log1pf(expf(-fabsf(x)))) - x * t;
        }
    }

    __shared__ float s0[256], s1[256], s2[256], s3[256];
    int t = threadIdx.x;
    s0[t] = lobj; s1[t] = liou; s2[t] = lcls; s3[t] = fgf;
    __syncthreads();
    for (int o = 128; o > 0; o >>= 1) {
        if (t < o) { s0[t] += s0[t + o]; s1[t] += s1[t + o]; s2[t] += s2[t + o]; s3[t] += s3[t + o]; }
        __syncthreads();
    }
    if (t == 0) {
        partials[blockIdx.x * 4 + 0] = s0[0];
        partials[blockIdx.x * 4 + 1] = s1[0];
        partials[blockIdx.x * 4 + 2] = s2[0];
        partials[blockIdx.x * 4 + 3] = s3[0];
    }
}

__global__ __launch_bounds__(256) void k_final(const float* __restrict__ partials, int nblocks,
                                               const int* __restrict__ num_gts, float* __restrict__ out) {
    __shared__ float s0[256], s1[256], s2[256], s3[256];
    int t = threadIdx.x;
    float a0 = 0, a1 = 0, a2 = 0, a3 = 0;
    for (int i = t; i < nblocks; i += 256) {
        a0 += partials[i * 4 + 0];
        a1 += partials[i * 4 + 1];
        a2 += partials[i * 4 + 2];
        a3 += partials[i * 4 + 3];
    }
    s0[t] = a0; s1[t] = a1; s2[t] = a2; s3[t] = a3;
    __syncthreads();
    for (int o = 128; o > 0; o >>= 1) {
        if (t < o) { s0[t] += s0[t + o]; s1[t] += s1[t + o]; s2[t] += s2[t + o]; s3[t] += s3[t + o]; }
        __syncthreads();
    }
    if (t == 0) {
        int sg = 0;
        for (int i = 0; i < NB; i++) sg += num_gts[i];
        float num_fg = fmaxf(s3[0], 1.0f);
        float li5 = 5.0f * (s1[0] / num_fg);
        float lo = s0[0] / num_fg;
        float lcx = s2[0] / num_fg;
        out[0] = li5 + lo + lcx;
        out[1] = li5;
        out[2] = lo;
        out[3] = lcx;
        out[4] = num_fg / fmaxf((float)sg, 1.0f);
    }
}

extern "C" void kernel_launch(void* const* d_in, const int* in_sizes, int n_in,
                              void* d_out, int out_size, void* d_ws, size_t ws_size,
                              hipStream_t stream) {
    const float* l0 = (const float*)d_in[0];
    const float* l1 = (const float*)d_in[1];
    const float* gt_boxes = (const float*)d_in[2];
    const int* gt_classes = (const int*)d_in[3];
    const int* num_gts = (const int*)d_in[4];
    float* out = (float*)d_out;

    char* w = (char*)d_ws;
    float4* dec = (float4*)(w);                            // 2,048,000
    float* qq   = (float*)(w + 2048000);                   // 10,240,000
    unsigned long long* fgw = (unsigned long long*)(w + 12288000); // 16,384
    unsigned int* cm = (unsigned int*)(w + 12304384);      // 512,000
    unsigned int* bg = (unsigned int*)(w + 12816384);      // 512,000
    float* partials = (float*)(w + 13328384);              // 8,000

    (void)n_in; (void)in_sizes; (void)out_size; (void)ws_size;

    k_decode<<<dim3(8, NB), 256, 0, stream>>>(l0, l1, gt_boxes, num_gts, dec, qq, fgw, cm, bg);
    k_assign<<<(NB * NM) / 4, 256, 0, stream>>>(gt_boxes, gt_classes, num_gts, dec, qq, fgw, cm, bg);
    k_resolve<<<(NB * NA) / 256, 256, 0, stream>>>(l0, l1, gt_boxes, gt_classes, dec, cm, bg, partials);
    k_final<<<1, 256, 0, stream>>>(partials, (NB * NA) / 256, num_gts, out);
}

// Round 6
// 144.412 us; speedup vs baseline: 1.0827x; 1.0827x over previous
//
#include <hip/hip_runtime.h>
#include <cfloat>
#include <climits>

#define NB 64
#define NA 2000
#define NA0 1600
#define NC 20
#define NM 100

__device__ __forceinline__ void anchor_geom(int a, float& axc, float& ayc, float& st) {
    if (a < NA0) {
        st = 16.0f;
        int x = a % 40, y = a / 40;
        axc = ((float)x + 0.5f) * 16.0f;
        ayc = ((float)y + 0.5f) * 16.0f;
    } else {
        st = 32.0f;
        int aa = a - NA0;
        int x = aa % 20, y = aa / 20;
        axc = ((float)x + 0.5f) * 32.0f;
        ayc = ((float)y + 0.5f) * 32.0f;
    }
}

// SimOTA cost; must match k_assign's inline computation bit-exactly.
__device__ __forceinline__ float cost_pair(const float4 g, float clsc, const float4 pb,
                                           float axc, float ayc, float st, bool fc) {
    float tlx = fmaxf(g.x - 0.5f * g.z, pb.x - 0.5f * pb.z);
    float tly = fmaxf(g.y - 0.5f * g.w, pb.y - 0.5f * pb.w);
    float brx = fminf(g.x + 0.5f * g.z, pb.x + 0.5f * pb.z);
    float bry = fminf(g.y + 0.5f * g.w, pb.y + 0.5f * pb.w);
    float inter = (brx - tlx) * (bry - tly);
    bool ok = (tlx < brx) && (tly < bry);
    inter = ok ? inter : 0.0f;
    float iou = inter / ((g.z * g.w + pb.z * pb.w) - inter + 1e-16f);
    bool ib = (axc > g.x - 0.5f * g.z) && (axc < g.x + 0.5f * g.z)
           && (ayc > g.y - 0.5f * g.w) && (ayc < g.y + 0.5f * g.w);
    bool ic = (axc > g.x - 2.5f * st) && (axc < g.x + 2.5f * st)
           && (ayc > g.y - 2.5f * st) && (ayc < g.y + 2.5f * st);
    return ((clsc - 3.0f * __logf(iou + 1e-8f)) + ((ib && ic) ? 0.0f : 1e5f)) + (fc ? 0.0f : 1e9f);
}

__global__ __launch_bounds__(256) void k_decode(const float* __restrict__ l0, const float* __restrict__ l1,
                                                const float* __restrict__ gt_boxes, const int* __restrict__ num_gts,
                                                float4* __restrict__ dec, float* __restrict__ qq,
                                                unsigned long long* __restrict__ fgw, unsigned int* __restrict__ cm,
                                                unsigned int* __restrict__ counter) {
    int b = blockIdx.y;
    int a = blockIdx.x * 256 + threadIdx.x;
    int lane = threadIdx.x & 63;
    __shared__ float4 sext[NM];   // gl, gr, gt, gb
    __shared__ float2 sctr[NM];   // g.x, g.y
    __shared__ int sng;
    if (threadIdx.x < NM) {
        float4 g = ((const float4*)gt_boxes)[b * NM + threadIdx.x];
        g.x *= 640.0f; g.y *= 640.0f; g.z *= 640.0f; g.w *= 640.0f;
        sext[threadIdx.x] = make_float4(g.x - 0.5f * g.z, g.x + 0.5f * g.z,
                                        g.y - 0.5f * g.w, g.y + 0.5f * g.w);
        sctr[threadIdx.x] = make_float2(g.x, g.y);
    }
    if (threadIdx.x == 0) sng = num_gts[b];
    if (b == 0 && blockIdx.x == 0 && threadIdx.x == 0) *counter = 0u;
    __syncthreads();
    if (a >= NA) return;

    float v[25];
    if (a < NA0) {
        const float* p = l0 + (size_t)b * 25 * NA0 + a;
#pragma unroll
        for (int c = 0; c < 25; c++) v[c] = p[(size_t)c * NA0];
    } else {
        const float* p = l1 + (size_t)b * 25 * 400 + (a - NA0);
#pragma unroll
        for (int c = 0; c < 25; c++) v[c] = p[(size_t)c * 400];
    }
    float axc, ayc, st;
    anchor_geom(a, axc, ayc, st);
    float gx, gy;
    if (a < NA0) { gx = (float)(a % 40); gy = (float)(a / 40); }
    else { int aa = a - NA0; gx = (float)(aa % 20); gy = (float)(aa / 20); }
    float4 pb;
    pb.x = (v[0] + gx) * st;
    pb.y = (v[1] + gy) * st;
    pb.z = expf(v[2]) * st;
    pb.w = expf(v[3]) * st;
    dec[(size_t)b * NA + a] = pb;

    float sob = 1.0f / (1.0f + __expf(-v[4]));
    float d[NC];
    float s = 0.0f;
#pragma unroll
    for (int c = 0; c < NC; c++) {
        float sc = 1.0f / (1.0f + __expf(-v[5 + c]));
        float p = sqrtf(sc * sob);
        float lp = __logf(p + 1e-12f);
        float lq = __logf(1.0f - p + 1e-12f);
        s += -lq;
        d[c] = lq - lp;
    }
#pragma unroll
    for (int c = 0; c < NC; c++)
        qq[((size_t)b * NC + c) * NA + a] = s + d[c];

    int ng = sng;
    int f = 0;
    float rst = 2.5f * st;
    for (int m = 0; m < ng; m++) {
        float4 e = sext[m];
        float2 cc = sctr[m];
        bool ib = (axc > e.x) && (axc < e.y) && (ayc > e.z) && (ayc < e.w);
        bool ic = (axc > cc.x - rst) && (axc < cc.x + rst) && (ayc > cc.y - rst) && (ayc < cc.y + rst);
        if (ib || ic) { f = 1; break; }
    }
    unsigned long long mk = __ballot(f);
    if (lane == 0) fgw[(size_t)b * 32 + (a >> 6)] = mk;
    cm[(size_t)b * NA + a] = 0;
}

// one wave per (b, m) row; 4 waves per block. Packed u32 keys + destructive extraction.
__global__ __launch_bounds__(256, 4) void k_assign(const float* __restrict__ gt_boxes, const int* __restrict__ gt_classes,
                                                   const int* __restrict__ num_gts, const float4* __restrict__ dec,
                                                   const float* __restrict__ qq, const unsigned long long* __restrict__ fgw,
                                                   unsigned int* __restrict__ cm) {
    int wave = threadIdx.x >> 6;
    int lane = threadIdx.x & 63;
    int row = blockIdx.x * 4 + wave;
    int b = row / NM, m = row - b * NM;
    if (m >= num_gts[b]) return;

    float4 g = ((const float4*)gt_boxes)[b * NM + m];
    g.x *= 640.0f; g.y *= 640.0f; g.z *= 640.0f; g.w *= 640.0f;
    int tc = gt_classes[b * NM + m];
    const float* qrow = qq + ((size_t)b * NC + tc) * NA;
    size_t bNA = (size_t)b * NA;

    float glx = g.x - 0.5f * g.z, grx = g.x + 0.5f * g.z;
    float gty = g.y - 0.5f * g.w, gby = g.y + 0.5f * g.w;
    float areag = g.z * g.w;
    float c16l = g.x - 40.0f, c16r = g.x + 40.0f, c16t = g.y - 40.0f, c16b = g.y + 40.0f;
    float c32l = g.x - 80.0f, c32r = g.x + 80.0f, c32t = g.y - 80.0f, c32b = g.y + 80.0f;

    // ik: packed iou keys (desc-extract); ck: packed cost keys (asc-extract). idx in low 11 bits.
    unsigned int ik[32], ck[32];
#pragma unroll
    for (int j = 0; j < 32; j++) {
        int a = j * 64 + lane;
        bool inr = (j < 31) || (lane < 16);
        float stj = (j < 25) ? 16.0f : 32.0f;
        int rel = (j < 25) ? a : (a - NA0);
        int W = (j < 25) ? 40 : 20;
        int gyv = rel / W;
        int gxv = rel - gyv * W;
        float axc = ((float)gxv + 0.5f) * stj;
        float ayc = ((float)gyv + 0.5f) * stj;
        unsigned long long fw = fgw[(size_t)b * 32 + j];
        bool fc = (fw >> lane) & 1ULL;
        float4 pb = make_float4(0.f, 0.f, 1.f, 1.f);
        float clsc = 0.0f;
        if (inr) { pb = dec[bNA + a]; clsc = qrow[a]; }
        float tlx = fmaxf(glx, pb.x - 0.5f * pb.z);
        float tly = fmaxf(gty, pb.y - 0.5f * pb.w);
        float brx = fminf(grx, pb.x + 0.5f * pb.z);
        float bry = fminf(gby, pb.y + 0.5f * pb.w);
        float inter = (brx - tlx) * (bry - tly);
        bool ok = (tlx < brx) && (tly < bry);
        inter = ok ? inter : 0.0f;
        float iou = inter / ((areag + pb.z * pb.w) - inter + 1e-16f);
        bool ib = (axc > glx) && (axc < grx) && (ayc > gty) && (ayc < gby);
        bool ic = (j < 25) ? ((axc > c16l) && (axc < c16r) && (ayc > c16t) && (ayc < c16b))
                           : ((axc > c32l) && (axc < c32r) && (ayc > c32t) && (ayc < c32b));
        float cc = ((clsc - 3.0f * __logf(iou + 1e-8f)) + ((ib && ic) ? 0.0f : 1e5f)) + (fc ? 0.0f : 1e9f);
        float im = fc ? iou : 0.0f;
        ik[j] = inr ? ((__float_as_uint(im) & 0xFFFFF800u) | (unsigned)a) : 0u;
        ck[j] = inr ? ((__float_as_uint(cc) & 0xFFFFF800u) | (unsigned)a) : 0xFFFFFFFFu;
    }

    // Phase A: dk = max(1, trunc(sum of top-10 masked IoUs)) via destructive max-extraction.
    // Early break (uniform vector compare): once max value bits are 0, remaining adds are +0.0f.
    float s10 = 0.0f;
#pragma unroll 1
    for (int k = 0; k < 10; k++) {
        unsigned int t[16];
#pragma unroll
        for (int h = 0; h < 16; h++) t[h] = max(ik[2 * h], ik[2 * h + 1]);
#pragma unroll
        for (int w = 8; w >= 1; w >>= 1)
#pragma unroll
            for (int h = 0; h < w; h++) t[h] = max(t[h], t[h + w]);
        unsigned int mx = t[0];
#pragma unroll
        for (int o = 1; o < 64; o <<= 1) {
            unsigned int ov = (unsigned int)__shfl_xor((int)mx, o);
            mx = max(mx, ov);
        }
        if ((mx & 0xFFFFF800u) == 0u) break;
        s10 += __uint_as_float(mx & 0xFFFFF800u);
#pragma unroll
        for (int j = 0; j < 32; j++) ik[j] = (ik[j] == mx) ? 0u : ik[j];
    }
    int dk = (int)s10;
    if (dk < 1) dk = 1;

    // Phase B: dk destructive min-extractions on cost keys; mark matches
    unsigned int mb = 0;
#pragma unroll 1
    for (int k = 0; k < dk; k++) {
        unsigned int t[16];
#pragma unroll
        for (int h = 0; h < 16; h++) t[h] = min(ck[2 * h], ck[2 * h + 1]);
#pragma unroll
        for (int w = 8; w >= 1; w >>= 1)
#pragma unroll
            for (int h = 0; h < w; h++) t[h] = min(t[h], t[h + w]);
        unsigned int mn = t[0];
#pragma unroll
        for (int o = 1; o < 64; o <<= 1) {
            unsigned int ov = (unsigned int)__shfl_xor((int)mn, o);
            mn = min(mn, ov);
        }
#pragma unroll
        for (int j = 0; j < 32; j++) {
            bool e = (ck[j] == mn);
            mb |= e ? (1u << j) : 0u;
            ck[j] = e ? 0xFFFFFFFFu : ck[j];
        }
    }

    unsigned int inc = (1u << 20) + (unsigned)m;
#pragma unroll
    for (int j = 0; j < 32; j++) {
        if ((mb >> j) & 1u) atomicAdd(&cm[bNA + j * 64 + lane], inc);
    }
}

// Compact list of conflicted anchors (cnt >= 2).
__global__ __launch_bounds__(256) void k_detect(const unsigned int* __restrict__ cm,
                                                unsigned int* __restrict__ list,
                                                unsigned int* __restrict__ counter) {
    int idx = blockIdx.x * 256 + threadIdx.x;
    if ((cm[idx] >> 20) >= 2u) {
        unsigned int pos = atomicAdd(counter, 1u);
        list[pos] = (unsigned int)idx;
    }
}

// One wave per conflicted anchor (grid-stride): lanes parallelize over GT rows,
// truncated-key argmin (first occurrence), overwrite cm with (1<<20)|best_m.
__global__ __launch_bounds__(256) void k_conflict(const float* __restrict__ gt_boxes, const int* __restrict__ gt_classes,
                                                  const int* __restrict__ num_gts, const float4* __restrict__ dec,
                                                  const float* __restrict__ qq, const unsigned long long* __restrict__ fgw,
                                                  unsigned int* __restrict__ cm,
                                                  const unsigned int* __restrict__ list,
                                                  const unsigned int* __restrict__ counter) {
    int wid = (blockIdx.x * 256 + threadIdx.x) >> 6;
    int lane = threadIdx.x & 63;
    int nw = (gridDim.x * 256) >> 6;
    int cnt = (int)*counter;
    for (int i = wid; i < cnt; i += nw) {
        int idx = (int)list[i];
        int b = idx / NA, a = idx - b * NA;
        int ng = num_gts[b];
        float4 pb = dec[idx];
        float axc, ayc, st;
        anchor_geom(a, axc, ayc, st);
        bool fc = (fgw[(size_t)b * 32 + (a >> 6)] >> (a & 63)) & 1ULL;
        unsigned int best = 0xFFFFFFFFu;
#pragma unroll
        for (int half = 0; half < 2; half++) {
            int m = half * 64 + lane;
            if (m < ng) {
                float4 g = ((const float4*)gt_boxes)[b * NM + m];
                g.x *= 640.0f; g.y *= 640.0f; g.z *= 640.0f; g.w *= 640.0f;
                int tcm = gt_classes[b * NM + m];
                float clsc = qq[((size_t)b * NC + tcm) * NA + a];
                float cc = cost_pair(g, clsc, pb, axc, ayc, st, fc);
                unsigned int key = (__float_as_uint(cc) & 0xFFFFF800u) | (unsigned)m;
                best = min(best, key);
            }
        }
#pragma unroll
        for (int o = 1; o < 64; o <<= 1) {
            unsigned int ov = (unsigned int)__shfl_xor((int)best, o);
            best = min(best, ov);
        }
        if (lane == 0) cm[idx] = (1u << 20) | (best & 0x7FFu);
    }
}

__global__ __launch_bounds__(256) void k_resolve(const float* __restrict__ l0, const float* __restrict__ l1,
                                                 const float* __restrict__ gt_boxes, const int* __restrict__ gt_classes,
                                                 const float4* __restrict__ dec,
                                                 const unsigned int* __restrict__ cm,
                                                 float* __restrict__ partials) {
    int idx = blockIdx.x * 256 + threadIdx.x;
    int b = idx / NA, a = idx - b * NA;

    float objv;
    if (a < NA0) objv = l0[((size_t)b * 25 + 4) * NA0 + a];
    else         objv = l1[((size_t)b * 25 + 4) * 400 + (a - NA0)];

    unsigned int word = cm[idx];
    bool fg = (word >> 20) > 0;
    float fgf = fg ? 1.0f : 0.0f;
    float lobj = (fmaxf(objv, 0.0f) + log1pf(expf(-fabsf(objv)))) - objv * fgf;
    float liou = 0.0f, lcls = 0.0f;

    if (fg) {
        float4 pb = dec[idx];
        int m = (int)(word & 0xFFFFFu);
        float4 g = ((const float4*)gt_boxes)[b * NM + m];
        g.x *= 640.0f; g.y *= 640.0f; g.z *= 640.0f; g.w *= 640.0f;
        float tlx = fmaxf(pb.x - 0.5f * pb.z, g.x - 0.5f * g.z);
        float tly = fmaxf(pb.y - 0.5f * pb.w, g.y - 0.5f * g.w);
        float brx = fminf(pb.x + 0.5f * pb.z, g.x + 0.5f * g.z);
        float bry = fminf(pb.y + 0.5f * pb.w, g.y + 0.5f * g.w);
        float inter = (brx - tlx) * (bry - tly);
        bool ok = (tlx < brx) && (tly < bry);
        inter = ok ? inter : 0.0f;
        float iou = inter / ((pb.z * pb.w + g.z * g.w) - inter + 1e-16f);
        liou = 1.0f - iou * iou;
        float piou = iou;
        int tcm = gt_classes[b * NM + m];
#pragma unroll
        for (int c2 = 0; c2 < NC; c2++) {
            float x;
            if (a < NA0) x = l0[((size_t)b * 25 + 5 + c2) * NA0 + a];
            else         x = l1[((size_t)b * 25 + 5 + c2) * 400 + (a - NA0)];
            float t = (c2 == tcm) ? piou : 0.0f;
            lcls += (fmaxf(x, 0.0f) + log1pf(expf(-fabsf(x)))) - x * t;
        }
    }

    __shared__ float s0[256], s1[256], s2[256], s3[256];
    int t = threadIdx.x;
    s0[t] = lobj; s1[t] = liou; s2[t] = lcls; s3[t] = fgf;
    __syncthreads();
    for (int o = 128; o > 0; o >>= 1) {
        if (t < o) { s0[t] += s0[t + o]; s1[t] += s1[t + o]; s2[t] += s2[t + o]; s3[t] += s3[t + o]; }
        __syncthreads();
    }
    if (t == 0) {
        partials[blockIdx.x * 4 + 0] = s0[0];
        partials[blockIdx.x * 4 + 1] = s1[0];
        partials[blockIdx.x * 4 + 2] = s2[0];
        partials[blockIdx.x * 4 + 3] = s3[0];
    }
}

__global__ __launch_bounds__(256) void k_final(const float* __restrict__ partials, int nblocks,
                                               const int* __restrict__ num_gts, float* __restrict__ out) {
    __shared__ float s0[256], s1[256], s2[256], s3[256];
    int t = threadIdx.x;
    float a0 = 0, a1 = 0, a2 = 0, a3 = 0;
    for (int i = t; i < nblocks; i += 256) {
        a0 += partials[i * 4 + 0];
        a1 += partials[i * 4 + 1];
        a2 += partials[i * 4 + 2];
        a3 += partials[i * 4 + 3];
    }
    s0[t] = a0; s1[t] = a1; s2[t] = a2; s3[t] = a3;
    __syncthreads();
    for (int o = 128; o > 0; o >>= 1) {
        if (t < o) { s0[t] += s0[t + o]; s1[t] += s1[t + o]; s2[t] += s2[t + o]; s3[t] += s3[t + o]; }
        __syncthreads();
    }
    if (t == 0) {
        int sg = 0;
        for (int i = 0; i < NB; i++) sg += num_gts[i];
        float num_fg = fmaxf(s3[0], 1.0f);
        float li5 = 5.0f * (s1[0] / num_fg);
        float lo = s0[0] / num_fg;
        float lcx = s2[0] / num_fg;
        out[0] = li5 + lo + lcx;
        out[1] = li5;
        out[2] = lo;
        out[3] = lcx;
        out[4] = num_fg / fmaxf((float)sg, 1.0f);
    }
}

extern "C" void kernel_launch(void* const* d_in, const int* in_sizes, int n_in,
                              void* d_out, int out_size, void* d_ws, size_t ws_size,
                              hipStream_t stream) {
    const float* l0 = (const float*)d_in[0];
    const float* l1 = (const float*)d_in[1];
    const float* gt_boxes = (const float*)d_in[2];
    const int* gt_classes = (const int*)d_in[3];
    const int* num_gts = (const int*)d_in[4];
    float* out = (float*)d_out;

    char* w = (char*)d_ws;
    float4* dec = (float4*)(w);                            // 2,048,000
    float* qq   = (float*)(w + 2048000);                   // 10,240,000
    unsigned long long* fgw = (unsigned long long*)(w + 12288000); // 16,384
    unsigned int* cm = (unsigned int*)(w + 12304384);      // 512,000
    unsigned int* list = (unsigned int*)(w + 12816384);    // 512,000
    float* partials = (float*)(w + 13328384);              // 8,000
    unsigned int* counter = (unsigned int*)(w + 13336384); // 4

    (void)n_in; (void)in_sizes; (void)out_size; (void)ws_size;

    k_decode<<<dim3(8, NB), 256, 0, stream>>>(l0, l1, gt_boxes, num_gts, dec, qq, fgw, cm, counter);
    k_assign<<<(NB * NM) / 4, 256, 0, stream>>>(gt_boxes, gt_classes, num_gts, dec, qq, fgw, cm);
    k_detect<<<(NB * NA) / 256, 256, 0, stream>>>(cm, list, counter);
    k_conflict<<<64, 256, 0, stream>>>(gt_boxes, gt_classes, num_gts, dec, qq, fgw, cm, list, counter);
    k_resolve<<<(NB * NA) / 256, 256, 0, stream>>>(l0, l1, gt_boxes, gt_classes, dec, cm, partials);
    k_final<<<1, 256, 0, stream>>>(partials, (NB * NA) / 256, num_gts, out);
}

// Round 7
// 84.675 us; speedup vs baseline: 1.8466x; 1.7055x over previous
//
#include <hip/hip_runtime.h>
#include <cfloat>
#include <climits>

#define NB 64
#define NA 2000
#define NAP 2048
#define NA0 1600
#define NC 20
#define NM 100

__device__ __forceinline__ void anchor_geom(int a, float& axc, float& ayc, float& st) {
    if (a < NA0) {
        st = 16.0f;
        int x = a % 40, y = a / 40;
        axc = ((float)x + 0.5f) * 16.0f;
        ayc = ((float)y + 0.5f) * 16.0f;
    } else {
        st = 32.0f;
        int aa = a - NA0;
        int x = aa % 20, y = aa / 20;
        axc = ((float)x + 0.5f) * 32.0f;
        ayc = ((float)y + 0.5f) * 32.0f;
    }
}

// SimOTA cost; must match k_assign's inline computation bit-exactly.
__device__ __forceinline__ float cost_pair(const float4 g, float clsc, const float4 pb,
                                           float axc, float ayc, float st, bool fc) {
    float tlx = fmaxf(g.x - 0.5f * g.z, pb.x - 0.5f * pb.z);
    float tly = fmaxf(g.y - 0.5f * g.w, pb.y - 0.5f * pb.w);
    float brx = fminf(g.x + 0.5f * g.z, pb.x + 0.5f * pb.z);
    float bry = fminf(g.y + 0.5f * g.w, pb.y + 0.5f * pb.w);
    float inter = (brx - tlx) * (bry - tly);
    bool ok = (tlx < brx) && (tly < bry);
    inter = ok ? inter : 0.0f;
    float iou = inter / ((g.z * g.w + pb.z * pb.w) - inter + 1e-16f);
    bool ib = (axc > g.x - 0.5f * g.z) && (axc < g.x + 0.5f * g.z)
           && (ayc > g.y - 0.5f * g.w) && (ayc < g.y + 0.5f * g.w);
    bool ic = (axc > g.x - 2.5f * st) && (axc < g.x + 2.5f * st)
           && (ayc > g.y - 2.5f * st) && (ayc < g.y + 2.5f * st);
    return ((clsc - 3.0f * __logf(iou + 1e-8f)) + ((ib && ic) ? 0.0f : 1e5f)) + (fc ? 0.0f : 1e9f);
}

__global__ __launch_bounds__(256) void k_decode(const float* __restrict__ l0, const float* __restrict__ l1,
                                                const float* __restrict__ gt_boxes, const int* __restrict__ num_gts,
                                                float4* __restrict__ dec, float* __restrict__ qq,
                                                unsigned long long* __restrict__ fgw, unsigned int* __restrict__ cm,
                                                unsigned int* __restrict__ counter) {
    int b = blockIdx.y;
    int a = blockIdx.x * 256 + threadIdx.x;   // 0..2047
    int lane = threadIdx.x & 63;
    __shared__ float4 sext[NM];   // gl, gr, gt, gb
    __shared__ float2 sctr[NM];   // g.x, g.y
    __shared__ int sng;
    if (threadIdx.x < NM) {
        float4 g = ((const float4*)gt_boxes)[b * NM + threadIdx.x];
        g.x *= 640.0f; g.y *= 640.0f; g.z *= 640.0f; g.w *= 640.0f;
        sext[threadIdx.x] = make_float4(g.x - 0.5f * g.z, g.x + 0.5f * g.z,
                                        g.y - 0.5f * g.w, g.y + 0.5f * g.w);
        sctr[threadIdx.x] = make_float2(g.x, g.y);
    }
    if (threadIdx.x == 0) sng = num_gts[b];
    if (b == 0 && blockIdx.x == 0 && threadIdx.x == 0) *counter = 0u;
    __syncthreads();

    bool real = a < NA;
    size_t pidx = (size_t)b * NAP + a;

    if (!real) {
        // pad anchor: zero everything; fc bit = 0 via ballot(0)
        dec[pidx] = make_float4(0.f, 0.f, 0.f, 0.f);
#pragma unroll
        for (int c = 0; c < NC; c++) qq[((size_t)b * NC + c) * NAP + a] = 0.0f;
        cm[pidx] = 0;
        unsigned long long mk = __ballot(0);
        if (lane == 0) fgw[(size_t)b * 32 + (a >> 6)] = mk;
        return;
    }

    float v[25];
    if (a < NA0) {
        const float* p = l0 + (size_t)b * 25 * NA0 + a;
#pragma unroll
        for (int c = 0; c < 25; c++) v[c] = p[(size_t)c * NA0];
    } else {
        const float* p = l1 + (size_t)b * 25 * 400 + (a - NA0);
#pragma unroll
        for (int c = 0; c < 25; c++) v[c] = p[(size_t)c * 400];
    }
    float axc, ayc, st;
    anchor_geom(a, axc, ayc, st);
    float gx, gy;
    if (a < NA0) { gx = (float)(a % 40); gy = (float)(a / 40); }
    else { int aa = a - NA0; gx = (float)(aa % 20); gy = (float)(aa / 20); }
    float4 pb;
    pb.x = (v[0] + gx) * st;
    pb.y = (v[1] + gy) * st;
    pb.z = expf(v[2]) * st;
    pb.w = expf(v[3]) * st;
    dec[pidx] = pb;

    float sob = 1.0f / (1.0f + __expf(-v[4]));
    float d[NC];
    float s = 0.0f;
#pragma unroll
    for (int c = 0; c < NC; c++) {
        float sc = 1.0f / (1.0f + __expf(-v[5 + c]));
        float p = sqrtf(sc * sob);
        float lp = __logf(p + 1e-12f);
        float lq = __logf(1.0f - p + 1e-12f);
        s += -lq;
        d[c] = lq - lp;
    }
#pragma unroll
    for (int c = 0; c < NC; c++)
        qq[((size_t)b * NC + c) * NAP + a] = s + d[c];

    int ng = sng;
    int f = 0;
    float rst = 2.5f * st;
    for (int m = 0; m < ng; m++) {
        float4 e = sext[m];
        float2 cc = sctr[m];
        bool ib = (axc > e.x) && (axc < e.y) && (ayc > e.z) && (ayc < e.w);
        bool ic = (axc > cc.x - rst) && (axc < cc.x + rst) && (ayc > cc.y - rst) && (ayc < cc.y + rst);
        if (ib || ic) { f = 1; break; }
    }
    unsigned long long mk = __ballot(f);
    if (lane == 0) fgw[(size_t)b * 32 + (a >> 6)] = mk;
    cm[pidx] = 0;
}

// one wave per (b, m) row; 4 waves per block. Packed u32 keys + destructive extraction.
// Natural register allocation (NO min-waves bound: forcing 4/EU spilled ik/ck -> 184MB scratch, r6).
__global__ __launch_bounds__(256) void k_assign(const float* __restrict__ gt_boxes, const int* __restrict__ gt_classes,
                                                const int* __restrict__ num_gts, const float4* __restrict__ dec,
                                                const float* __restrict__ qq, const unsigned long long* __restrict__ fgw,
                                                unsigned int* __restrict__ cm) {
    int wave = threadIdx.x >> 6;
    int lane = threadIdx.x & 63;
    int row = blockIdx.x * 4 + wave;
    int b = row / NM, m = row - b * NM;
    if (m >= num_gts[b]) return;

    float4 g = ((const float4*)gt_boxes)[b * NM + m];
    g.x *= 640.0f; g.y *= 640.0f; g.z *= 640.0f; g.w *= 640.0f;
    int tc = gt_classes[b * NM + m];
    const float* qrow = qq + ((size_t)b * NC + tc) * NAP;
    size_t bNA = (size_t)b * NAP;

    float glx = g.x - 0.5f * g.z, grx = g.x + 0.5f * g.z;
    float gty = g.y - 0.5f * g.w, gby = g.y + 0.5f * g.w;
    float areag = g.z * g.w;
    float c16l = g.x - 40.0f, c16r = g.x + 40.0f, c16t = g.y - 40.0f, c16b = g.y + 40.0f;
    float c32l = g.x - 80.0f, c32r = g.x + 80.0f, c32t = g.y - 80.0f, c32b = g.y + 80.0f;

    // ik: packed iou keys (desc-extract); ck: packed cost keys (asc-extract). idx in low 11 bits.
    unsigned int ik[32], ck[32];
#pragma unroll
    for (int j = 0; j < 32; j++) {
        int a = j * 64 + lane;
        float stj = (j < 25) ? 16.0f : 32.0f;
        int rel = (j < 25) ? a : (a - NA0);
        int W = (j < 25) ? 40 : 20;
        int gyv = rel / W;
        int gxv = rel - gyv * W;
        float axc = ((float)gxv + 0.5f) * stj;
        float ayc = ((float)gyv + 0.5f) * stj;
        unsigned long long fw = fgw[(size_t)b * 32 + j];
        bool fc = (fw >> lane) & 1ULL;
        float4 pb = dec[bNA + a];
        float clsc = qrow[a];
        float tlx = fmaxf(glx, pb.x - 0.5f * pb.z);
        float tly = fmaxf(gty, pb.y - 0.5f * pb.w);
        float brx = fminf(grx, pb.x + 0.5f * pb.z);
        float bry = fminf(gby, pb.y + 0.5f * pb.w);
        float inter = (brx - tlx) * (bry - tly);
        bool ok = (tlx < brx) && (tly < bry);
        inter = ok ? inter : 0.0f;
        float iou = inter / ((areag + pb.z * pb.w) - inter + 1e-16f);
        bool ib = (axc > glx) && (axc < grx) && (ayc > gty) && (ayc < gby);
        bool ic = (j < 25) ? ((axc > c16l) && (axc < c16r) && (ayc > c16t) && (ayc < c16b))
                           : ((axc > c32l) && (axc < c32r) && (ayc > c32t) && (ayc < c32b));
        float cc = ((clsc - 3.0f * __logf(iou + 1e-8f)) + ((ib && ic) ? 0.0f : 1e5f)) + (fc ? 0.0f : 1e9f);
        float im = fc ? iou : 0.0f;
        ik[j] = (__float_as_uint(im) & 0xFFFFF800u) | (unsigned)a;
        ck[j] = (__float_as_uint(cc) & 0xFFFFF800u) | (unsigned)a;
    }

    // Phase A: dk = max(1, trunc(sum of top-10 masked IoUs)) via destructive max-extraction.
    // Early break (uniform vector compare): once max value bits are 0, remaining adds are +0.0f.
    float s10 = 0.0f;
#pragma unroll 1
    for (int k = 0; k < 10; k++) {
        unsigned int t[16];
#pragma unroll
        for (int h = 0; h < 16; h++) t[h] = max(ik[2 * h], ik[2 * h + 1]);
#pragma unroll
        for (int w = 8; w >= 1; w >>= 1)
#pragma unroll
            for (int h = 0; h < w; h++) t[h] = max(t[h], t[h + w]);
        unsigned int mx = t[0];
#pragma unroll
        for (int o = 1; o < 64; o <<= 1) {
            unsigned int ov = (unsigned int)__shfl_xor((int)mx, o);
            mx = max(mx, ov);
        }
        if ((mx & 0xFFFFF800u) == 0u) break;
        s10 += __uint_as_float(mx & 0xFFFFF800u);
#pragma unroll
        for (int j = 0; j < 32; j++) ik[j] = (ik[j] == mx) ? 0u : ik[j];
    }
    int dk = (int)s10;
    if (dk < 1) dk = 1;

    // Phase B: dk destructive min-extractions on cost keys; mark matches
    unsigned int mb = 0;
#pragma unroll 1
    for (int k = 0; k < dk; k++) {
        unsigned int t[16];
#pragma unroll
        for (int h = 0; h < 16; h++) t[h] = min(ck[2 * h], ck[2 * h + 1]);
#pragma unroll
        for (int w = 8; w >= 1; w >>= 1)
#pragma unroll
            for (int h = 0; h < w; h++) t[h] = min(t[h], t[h + w]);
        unsigned int mn = t[0];
#pragma unroll
        for (int o = 1; o < 64; o <<= 1) {
            unsigned int ov = (unsigned int)__shfl_xor((int)mn, o);
            mn = min(mn, ov);
        }
#pragma unroll
        for (int j = 0; j < 32; j++) {
            bool e = (ck[j] == mn);
            mb |= e ? (1u << j) : 0u;
            ck[j] = e ? 0xFFFFFFFFu : ck[j];
        }
    }

    unsigned int inc = (1u << 20) + (unsigned)m;
#pragma unroll
    for (int j = 0; j < 32; j++) {
        if ((mb >> j) & 1u) atomicAdd(&cm[bNA + j * 64 + lane], inc);
    }
}

// Compact list of conflicted anchors (cnt >= 2). idx is padded (b*2048+a).
__global__ __launch_bounds__(256) void k_detect(const unsigned int* __restrict__ cm,
                                                unsigned int* __restrict__ list,
                                                unsigned int* __restrict__ counter) {
    int idx = blockIdx.x * 256 + threadIdx.x;   // 0 .. 64*2048-1
    int a = idx & (NAP - 1);
    if (a < NA && (cm[idx] >> 20) >= 2u) {
        unsigned int pos = atomicAdd(counter, 1u);
        list[pos] = (unsigned int)idx;
    }
}

// One wave per conflicted anchor (grid-stride): lanes parallelize over GT rows,
// truncated-key argmin (first occurrence), overwrite cm with (1<<20)|best_m.
__global__ __launch_bounds__(256) void k_conflict(const float* __restrict__ gt_boxes, const int* __restrict__ gt_classes,
                                                  const int* __restrict__ num_gts, const float4* __restrict__ dec,
                                                  const float* __restrict__ qq, const unsigned long long* __restrict__ fgw,
                                                  unsigned int* __restrict__ cm,
                                                  const unsigned int* __restrict__ list,
                                                  const unsigned int* __restrict__ counter) {
    int wid = (blockIdx.x * 256 + threadIdx.x) >> 6;
    int lane = threadIdx.x & 63;
    int nw = (gridDim.x * 256) >> 6;
    int cnt = (int)*counter;
    for (int i = wid; i < cnt; i += nw) {
        int idx = (int)list[i];
        int b = idx >> 11, a = idx & (NAP - 1);
        int ng = num_gts[b];
        float4 pb = dec[idx];
        float axc, ayc, st;
        anchor_geom(a, axc, ayc, st);
        bool fc = (fgw[(size_t)b * 32 + (a >> 6)] >> (a & 63)) & 1ULL;
        unsigned int best = 0xFFFFFFFFu;
#pragma unroll
        for (int half = 0; half < 2; half++) {
            int m = half * 64 + lane;
            if (m < ng) {
                float4 g = ((const float4*)gt_boxes)[b * NM + m];
                g.x *= 640.0f; g.y *= 640.0f; g.z *= 640.0f; g.w *= 640.0f;
                int tcm = gt_classes[b * NM + m];
                float clsc = qq[((size_t)b * NC + tcm) * NAP + a];
                float cc = cost_pair(g, clsc, pb, axc, ayc, st, fc);
                unsigned int key = (__float_as_uint(cc) & 0xFFFFF800u) | (unsigned)m;
                best = min(best, key);
            }
        }
#pragma unroll
        for (int o = 1; o < 64; o <<= 1) {
            unsigned int ov = (unsigned int)__shfl_xor((int)best, o);
            best = min(best, ov);
        }
        if (lane == 0) cm[idx] = (1u << 20) | (best & 0x7FFu);
    }
}

__global__ __launch_bounds__(256) void k_resolve(const float* __restrict__ l0, const float* __restrict__ l1,
                                                 const float* __restrict__ gt_boxes, const int* __restrict__ gt_classes,
                                                 const float4* __restrict__ dec,
                                                 const unsigned int* __restrict__ cm,
                                                 float* __restrict__ partials) {
    int idx = blockIdx.x * 256 + threadIdx.x;    // 0 .. 64*2000-1 (logical)
    int b = idx / NA, a = idx - b * NA;
    size_t pidx = (size_t)b * NAP + a;

    float objv;
    if (a < NA0) objv = l0[((size_t)b * 25 + 4) * NA0 + a];
    else         objv = l1[((size_t)b * 25 + 4) * 400 + (a - NA0)];

    unsigned int word = cm[pidx];
    bool fg = (word >> 20) > 0;
    float fgf = fg ? 1.0f : 0.0f;
    float lobj = (fmaxf(objv, 0.0f) + log1pf(expf(-fabsf(objv)))) - objv * fgf;
    float liou = 0.0f, lcls = 0.0f;

    if (fg) {
        float4 pb = dec[pidx];
        int m = (int)(word & 0xFFFFFu);
        float4 g = ((const float4*)gt_boxes)[b * NM + m];
        g.x *= 640.0f; g.y *= 640.0f; g.z *= 640.0f; g.w *= 640.0f;
        float tlx = fmaxf(pb.x - 0.5f * pb.z, g.x - 0.5f * g.z);
        float tly = fmaxf(pb.y - 0.5f * pb.w, g.y - 0.5f * g.w);
        float brx = fminf(pb.x + 0.5f * pb.z, g.x + 0.5f * g.z);
        float bry = fminf(pb.y + 0.5f * pb.w, g.y + 0.5f * g.w);
        float inter = (brx - tlx) * (bry - tly);
        bool ok = (tlx < brx) && (tly < bry);
        inter = ok ? inter : 0.0f;
        float iou = inter / ((pb.z * pb.w + g.z * g.w) - inter + 1e-16f);
        liou = 1.0f - iou * iou;
        float piou = iou;
        int tcm = gt_classes[b * NM + m];
#pragma unroll
        for (int c2 = 0; c2 < NC; c2++) {
            float x;
            if (a < NA0) x = l0[((size_t)b * 25 + 5 + c2) * NA0 + a];
            else         x = l1[((size_t)b * 25 + 5 + c2) * 400 + (a - NA0)];
            float t = (c2 == tcm) ? piou : 0.0f;
            lcls += (fmaxf(x, 0.0f) + log1pf(expf(-fabsf(x)))) - x * t;
        }
    }

    __shared__ float s0[256], s1[256], s2[256], s3[256];
    int t = threadIdx.x;
    s0[t] = lobj; s1[t] = liou; s2[t] = lcls; s3[t] = fgf;
    __syncthreads();
    for (int o = 128; o > 0; o >>= 1) {
        if (t < o) { s0[t] += s0[t + o]; s1[t] += s1[t + o]; s2[t] += s2[t + o]; s3[t] += s3[t + o]; }
        __syncthreads();
    }
    if (t == 0) {
        partials[blockIdx.x * 4 + 0] = s0[0];
        partials[blockIdx.x * 4 + 1] = s1[0];
        partials[blockIdx.x * 4 + 2] = s2[0];
        partials[blockIdx.x * 4 + 3] = s3[0];
    }
}

__global__ __launch_bounds__(256) void k_final(const float* __restrict__ partials, int nblocks,
                                               const int* __restrict__ num_gts, float* __restrict__ out) {
    __shared__ float s0[256], s1[256], s2[256], s3[256];
    int t = threadIdx.x;
    float a0 = 0, a1 = 0, a2 = 0, a3 = 0;
    for (int i = t; i < nblocks; i += 256) {
        a0 += partials[i * 4 + 0];
        a1 += partials[i * 4 + 1];
        a2 += partials[i * 4 + 2];
        a3 += partials[i * 4 + 3];
    }
    s0[t] = a0; s1[t] = a1; s2[t] = a2; s3[t] = a3;
    __syncthreads();
    for (int o = 128; o > 0; o >>= 1) {
        if (t < o) { s0[t] += s0[t + o]; s1[t] += s1[t + o]; s2[t] += s2[t + o]; s3[t] += s3[t + o]; }
        __syncthreads();
    }
    if (t == 0) {
        int sg = 0;
        for (int i = 0; i < NB; i++) sg += num_gts[i];
        float num_fg = fmaxf(s3[0], 1.0f);
        float li5 = 5.0f * (s1[0] / num_fg);
        float lo = s0[0] / num_fg;
        float lcx = s2[0] / num_fg;
        out[0] = li5 + lo + lcx;
        out[1] = li5;
        out[2] = lo;
        out[3] = lcx;
        out[4] = num_fg / fmaxf((float)sg, 1.0f);
    }
}

extern "C" void kernel_launch(void* const* d_in, const int* in_sizes, int n_in,
                              void* d_out, int out_size, void* d_ws, size_t ws_size,
                              hipStream_t stream) {
    const float* l0 = (const float*)d_in[0];
    const float* l1 = (const float*)d_in[1];
    const float* gt_boxes = (const float*)d_in[2];
    const int* gt_classes = (const int*)d_in[3];
    const int* num_gts = (const int*)d_in[4];
    float* out = (float*)d_out;

    char* w = (char*)d_ws;
    float4* dec = (float4*)(w);                            // 64*2048*16 = 2,097,152
    float* qq   = (float*)(w + 2097152);                   // 64*20*2048*4 = 10,485,760
    unsigned long long* fgw = (unsigned long long*)(w + 12582912); // 16,384
    unsigned int* cm = (unsigned int*)(w + 12599296);      // 64*2048*4 = 524,288
    unsigned int* list = (unsigned int*)(w + 13123584);    // 512,000
    float* partials = (float*)(w + 13635584);              // 8,000
    unsigned int* counter = (unsigned int*)(w + 13643584); // 4

    (void)n_in; (void)in_sizes; (void)out_size; (void)ws_size;

    k_decode<<<dim3(8, NB), 256, 0, stream>>>(l0, l1, gt_boxes, num_gts, dec, qq, fgw, cm, counter);
    k_assign<<<(NB * NM) / 4, 256, 0, stream>>>(gt_boxes, gt_classes, num_gts, dec, qq, fgw, cm);
    k_detect<<<(NB * NAP) / 256, 256, 0, stream>>>(cm, list, counter);
    k_conflict<<<64, 256, 0, stream>>>(gt_boxes, gt_classes, num_gts, dec, qq, fgw, cm, list, counter);
    k_resolve<<<(NB * NA) / 256, 256, 0, stream>>>(l0, l1, gt_boxes, gt_classes, dec, cm, partials);
    k_final<<<1, 256, 0, stream>>>(partials, (NB * NA) / 256, num_gts, out);
}